// Round 6
// baseline (260.512 us; speedup 1.0000x reference)
//
#include <hip/hip_runtime.h>
#include <stdint.h>

// MultiHeadCrossAttention: B=4, Nq=1024, Nk=2048, QUERY_DIM=1024, KEY_DIM=768, H=16, D=64
// Inputs/outputs FLOAT32. Internally fp16 MFMA with f32 accumulate:
//   0) cvt: f32 -> fp16 copies of query/key/value/Wq/Wk/Wv/Wo in ws
//   1) fused QKV projection, ONE dispatch, 1280 blocks, 128x128 m97-structure tiles
//   2) flash attention (512 blocks x 8 waves, XCD-grouped bh, 2-phase pipeline, defer-max)
//   3) out = AO @ Wo^T + bo (f32), 128x128 tiles, dbuf counted-vmcnt (1 block/CU case)

typedef __attribute__((ext_vector_type(4))) float f32x4;
typedef __attribute__((ext_vector_type(8))) _Float16 half8;
typedef __attribute__((ext_vector_type(4))) _Float16 half4;
typedef __attribute__((ext_vector_type(2))) _Float16 half2v;
typedef __attribute__((ext_vector_type(4))) short short4v;
typedef __attribute__((ext_vector_type(8))) short short8;
typedef unsigned short u16;

__device__ __forceinline__ u16 f2h(float f){
  _Float16 h = (_Float16)f;
  return __builtin_bit_cast(unsigned short, h);
}

__device__ __forceinline__ void gload16(const void* g, void* lds){
  __builtin_amdgcn_global_load_lds((const __attribute__((address_space(1))) void*)g,
                                   (__attribute__((address_space(3))) void*)lds, 16, 0, 0);
}

// ---------- f32 -> fp16 pre-convert ----------
struct Seg { const float* s; u16* d; int n4; };
struct Cvt7 { Seg seg[7]; };

__global__ __launch_bounds__(256) void cvt_f32_f16(Cvt7 a){
  Seg sg = a.seg[blockIdx.y];
  const long stride = (long)gridDim.x * 256;
  for (long i = (long)blockIdx.x*256 + threadIdx.x; i < sg.n4; i += stride){
    f32x4 v = *(const f32x4*)(sg.s + i*4);
    short4v h;
    h[0] = (short)f2h(v[0]); h[1] = (short)f2h(v[1]);
    h[2] = (short)f2h(v[2]); h[3] = (short)f2h(v[3]);
    *(short4v*)(sg.d + i*4) = h;
  }
}

// Stage R rows x 128B (64 fp16/row) global->LDS, 16B-chunk XOR swizzle.
// LDS slot (r,b) holds global byte (r, b ^ ((r&7)<<4)); readers apply the same XOR.
// LDS dest base is wave-uniform (global_load_lds adds lane*16); the permutation is
// applied on the per-lane GLOBAL source address (guide rule #21).
template<int R, int THREADS>
__device__ __forceinline__ void stage_tile(const char* gbase, long gstride, char* lds, int tid){
  const int w = tid >> 6, lane = tid & 63;
  #pragma unroll
  for (int it = 0; it < R*8/THREADS; ++it){
    int c  = it*THREADS + w*64 + lane;       // 16B chunk id
    int r  = c >> 3;                         // row (8 chunks/row)
    int bs = (c & 7) << 4;
    int sb = bs ^ ((r & 7) << 4);            // inverse-swizzled source byte
    gload16(gbase + (long)r*gstride + sb, lds + (it*THREADS + w*64)*16);
  }
}

// 128x128 GEMM mainloop (m97 structure), BK=64, 4 waves (2x2), wave tile 64x64,
// acc[4][4], 16x16x32 f16 MFMA.  DBUF=0: single-buffered 32KB, 2 barriers/K-step
// (proven 874-912 TF shape; relies on >=2 resident blocks/CU for overlap).
// DBUF=1: double-buffered 64KB with counted vmcnt(8) (for 1-block/CU dispatches).
template<bool DBUF>
__device__ __forceinline__ void gemm128(const u16* A, const u16* Bt, int K,
                                        int row0, int col0, int tid,
                                        char* lds, f32x4 acc[4][4]){
  const int lane = tid & 63, w = tid >> 6;
  const int g = lane >> 4, lm = lane & 15;
  const int wr = (w >> 1) * 64, wc = (w & 1) * 64;
  const char* Ag = (const char*)A  + ((long)row0 * K) * 2;
  const char* Bg = (const char*)Bt + ((long)col0 * K) * 2;

  if (DBUF){
    stage_tile<128, 256>(Ag, (long)K*2, lds, tid);
    stage_tile<128, 256>(Bg, (long)K*2, lds + 16384, tid);
  }
  for (int k0 = 0; k0 < K; k0 += 64){
    char* cur;
    if (DBUF){
      cur = lds + ((k0 >> 6) & 1) * 32768;
      if (k0 + 64 < K){
        char* nxt = lds + ((((k0 >> 6) & 1) ^ 1)) * 32768;
        stage_tile<128, 256>(Ag + (long)(k0+64)*2, (long)K*2, nxt, tid);
        stage_tile<128, 256>(Bg + (long)(k0+64)*2, (long)K*2, nxt + 16384, tid);
        asm volatile("s_waitcnt vmcnt(8)" ::: "memory");
      } else {
        asm volatile("s_waitcnt vmcnt(0)" ::: "memory");
      }
      __builtin_amdgcn_s_barrier();
    } else {
      cur = lds;
      stage_tile<128, 256>(Ag + (long)k0*2, (long)K*2, cur, tid);
      stage_tile<128, 256>(Bg + (long)k0*2, (long)K*2, cur + 16384, tid);
      __syncthreads();
    }
    char* Al = cur, *Bl = cur + 16384;
    #pragma unroll
    for (int kk = 0; kk < 2; ++kk){
      half8 af[4], bfr[4];
      #pragma unroll
      for (int mi = 0; mi < 4; ++mi){
        int r = wr + mi*16 + lm;
        af[mi] = *(const half8*)(Al + r*128 + ((kk*64 + g*16) ^ ((r & 7) << 4)));
      }
      #pragma unroll
      for (int ni = 0; ni < 4; ++ni){
        int r = wc + ni*16 + lm;
        bfr[ni] = *(const half8*)(Bl + r*128 + ((kk*64 + g*16) ^ ((r & 7) << 4)));
      }
      #pragma unroll
      for (int mi = 0; mi < 4; ++mi)
        #pragma unroll
        for (int ni = 0; ni < 4; ++ni)
          acc[mi][ni] = __builtin_amdgcn_mfma_f32_16x16x32_f16(af[mi], bfr[ni], acc[mi][ni], 0, 0, 0);
    }
    if (DBUF) __builtin_amdgcn_s_barrier();
    else      __syncthreads();
  }
}

// Fused Q/K/V projections, 128x128 tiles. work ids: [0,256) Q, [256,768) K, [768,1280) V.
// Chunked XCD map (1280 = 8*160): consecutive work on one XCD -> A-panel L2 reuse.
__global__ __launch_bounds__(256)
void qkv_proj(const u16* __restrict__ qH, const u16* __restrict__ kH, const u16* __restrict__ vH,
              const u16* __restrict__ WqH, const u16* __restrict__ WkH, const u16* __restrict__ WvH,
              const float* __restrict__ bq, const float* __restrict__ bk, const float* __restrict__ bv,
              u16* __restrict__ Qw, u16* __restrict__ Kw, u16* __restrict__ Vtw)
{
  __shared__ __align__(128) char lds[32768];
  const int tid = threadIdx.x, lane = tid & 63, w = tid >> 6;
  const int g = lane >> 4, lm = lane & 15;

  int bid = (blockIdx.x & 7) * 160 + (blockIdx.x >> 3);   // 1280 = 8 * 160
  const u16 *A, *Bt; const float* bias; u16* out16;
  int K, logS, local; float scale = 1.0f;
  int which;
  if (bid < 256)      { which = 0; local = bid;       A = qH; Bt = WqH; bias = bq; out16 = Qw;  K = 1024; logS = 10; scale = 0.125f; }
  else if (bid < 768) { which = 1; local = bid - 256; A = kH; Bt = WkH; bias = bk; out16 = Kw;  K = 768;  logS = 11; }
  else                { which = 2; local = bid - 768; A = vH; Bt = WvH; bias = bv; out16 = Vtw; K = 768;  logS = 11; }
  const int rb = local >> 3, cb = local & 7;
  const int row0 = rb * 128, col0 = cb * 128;

  f32x4 acc[4][4];
  #pragma unroll
  for (int i = 0; i < 4; ++i)
    #pragma unroll
    for (int j = 0; j < 4; ++j) acc[i][j] = {0.f, 0.f, 0.f, 0.f};

  gemm128<false>(A, Bt, K, row0, col0, tid, lds, acc);

  const int wr = (w >> 1) * 64, wc = (w & 1) * 64;
  if (which != 2){
    // split-head epilogue: dst[((b*16+h)<<logS | s)*64 + d]
    #pragma unroll
    for (int mi = 0; mi < 4; ++mi)
      #pragma unroll
      for (int ni = 0; ni < 4; ++ni){
        int n = col0 + wc + ni*16 + lm;
        float bvv = bias[n];
        int h_ = n >> 6, d_ = n & 63;
        #pragma unroll
        for (int r = 0; r < 4; ++r){
          int m = row0 + wr + mi*16 + g*4 + r;
          int b_ = m >> logS, s_ = m & ((1 << logS) - 1);
          long dst = (((long)(b_*16 + h_) << logS) + s_) * 64 + d_;
          out16[dst] = f2h((acc[mi][ni][r] + bvv) * scale);
        }
      }
  } else {
    // V: transpose 128x128 tile through LDS (reuse the 32KB buffer), then
    // 16B-coalesced stores of V^T[(b*16+h)*64 + d][s]. T rows 256B, XOR-16B swizzle.
    // (loop ended with __syncthreads -> all LDS reads complete, safe to overwrite)
    #pragma unroll
    for (int mi = 0; mi < 4; ++mi)
      #pragma unroll
      for (int ni = 0; ni < 4; ++ni){
        int np = wc + ni*16 + lm;
        float bvv = bias[col0 + np];
        short4v h4;
        #pragma unroll
        for (int r = 0; r < 4; ++r) h4[r] = (short)f2h(acc[mi][ni][r] + bvv);
        int mb = (wr + mi*16 + g*4) * 2;
        *(short4v*)(lds + np*256 + (mb ^ ((np & 7) << 4))) = h4;
      }
    __syncthreads();
    const int b_ = row0 >> 11;
    #pragma unroll
    for (int pass = 0; pass < 8; ++pass){
      int idx = pass*256 + tid, row = idx >> 4, c = idx & 15;
      short8 v = *(const short8*)(lds + row*256 + ((c*16) ^ ((row & 7) << 4)));
      int ng = col0 + row, h_ = ng >> 6, d_ = ng & 63;
      long dst = ((long)(b_*16 + h_)*64 + d_)*2048 + (row0 & 2047) + c*8;
      *(short8*)(out16 + dst) = v;
    }
  }
}

// Flash attention: 512 blocks x 512 threads (8 waves x 16 q-rows). XCD-grouped bh.
// Double-buffered K/V staging with counted vmcnt(2). Swapped QK^T: lane holds a
// full P-row slice (q = lane&15); softmax = 2 shfl_xor; P feeds PV A-operand in
// regs with the SAME k-permutation pi(g,i) used for V's B-frag. Defer-max (T13).
__global__ __launch_bounds__(512, 4)
void attn_fused(const u16* __restrict__ Qw, const u16* __restrict__ Kw,
                const u16* __restrict__ Vtw, u16* __restrict__ AO)
{
  __shared__ __align__(128) char lds[32768];   // 2 x {K 8K | V 8K}
  const int tid = threadIdx.x, lane = tid & 63, w = tid >> 6;
  const int g = lane >> 4, lm = lane & 15;
  const int p = blockIdx.x;
  const int slot = p >> 3;
  const int bh = (p & 7) + ((slot & 7) << 3);
  const int qt = slot >> 3;
  const long qbase = (long)bh * 1024 * 64;
  const long kbase = (long)bh * 2048 * 64;
  const long vbase = (long)bh * 64 * 2048;

  const int q0 = qt*128 + w*16;
  half8 aQ[2];
  #pragma unroll
  for (int kk = 0; kk < 2; ++kk)
    aQ[kk] = *(const half8*)((const char*)Qw + (qbase + (long)(q0 + lm)*64 + kk*32 + g*8)*2);

  float mrun = -3e38f, lrun = 0.f;
  f32x4 O[4];
  #pragma unroll
  for (int di = 0; di < 4; ++di) O[di] = {0.f, 0.f, 0.f, 0.f};

  // prologue: stage tile 0 into buf0
  stage_tile<64, 512>((const char*)Kw  + kbase*2, 128,  lds, tid);
  stage_tile<64, 512>((const char*)Vtw + vbase*2, 4096, lds + 8192, tid);

  for (int kt = 0; kt < 2048; kt += 64){
    char* cur = lds + ((kt >> 6) & 1) * 16384;
    if (kt + 64 < 2048){
      char* nxt = lds + ((((kt >> 6) & 1) ^ 1)) * 16384;
      stage_tile<64, 512>((const char*)Kw  + (kbase + (long)(kt+64)*64)*2, 128,  nxt, tid);
      stage_tile<64, 512>((const char*)Vtw + (vbase + kt+64)*2,            4096, nxt + 8192, tid);
      asm volatile("s_waitcnt vmcnt(2)" ::: "memory");
    } else {
      asm volatile("s_waitcnt vmcnt(0)" ::: "memory");
    }
    __builtin_amdgcn_s_barrier();
    char* Klds = cur, *Vlds = cur + 8192;

    half8 kf[4][2];
    #pragma unroll
    for (int t = 0; t < 4; ++t)
      #pragma unroll
      for (int kk = 0; kk < 2; ++kk){
        int r = t*16 + lm;
        kf[t][kk] = *(const half8*)(Klds + r*128 + ((kk*64 + g*16) ^ ((r & 7) << 4)));
      }

    // S^T tiles: lane holds S[q=lm][kpos = kt + t*16 + g*4 + r]  (Q pre-scaled 1/8)
    f32x4 sc[4];
    #pragma unroll
    for (int t = 0; t < 4; ++t){
      f32x4 z = {0.f, 0.f, 0.f, 0.f};
      z = __builtin_amdgcn_mfma_f32_16x16x32_f16(kf[t][0], aQ[0], z, 0, 0, 0);
      z = __builtin_amdgcn_mfma_f32_16x16x32_f16(kf[t][1], aQ[1], z, 0, 0, 0);
      sc[t] = z;
    }
    // online softmax with defer-max (skip rescale while max grows < 8)
    float pm = sc[0][0];
    #pragma unroll
    for (int t = 0; t < 4; ++t)
      #pragma unroll
      for (int r = 0; r < 4; ++r) pm = fmaxf(pm, sc[t][r]);
    pm = fmaxf(pm, __shfl_xor(pm, 16));
    pm = fmaxf(pm, __shfl_xor(pm, 32));
    if (!__all(pm <= mrun + 8.0f)){
      float mnew = fmaxf(mrun, pm);
      float fac  = __expf(mrun - mnew);
      lrun *= fac;
      float frow[4];
      #pragma unroll
      for (int r = 0; r < 4; ++r) frow[r] = __shfl(fac, (lane & 48) | (g*4 + r));
      #pragma unroll
      for (int di = 0; di < 4; ++di){
        O[di][0] *= frow[0]; O[di][1] *= frow[1];
        O[di][2] *= frow[2]; O[di][3] *= frow[3];
      }
      mrun = mnew;
    }
    float ls = 0.f;
    #pragma unroll
    for (int t = 0; t < 4; ++t)
      #pragma unroll
      for (int r = 0; r < 4; ++r){ float pv = __expf(sc[t][r] - mrun); sc[t][r] = pv; ls += pv; }
    ls += __shfl_xor(ls, 16);
    ls += __shfl_xor(ls, 32);
    lrun += ls;

    // pack P (rtz pair-convert): pa[kh][j*4+r] = sc[kh*2+j][r]
    half8 pa[2];
    #pragma unroll
    for (int kh = 0; kh < 2; ++kh)
      #pragma unroll
      for (int j = 0; j < 2; ++j){
        int t = kh*2 + j;
        half2v p01 = __builtin_bit_cast(half2v, __builtin_amdgcn_cvt_pkrtz(sc[t][0], sc[t][1]));
        half2v p23 = __builtin_bit_cast(half2v, __builtin_amdgcn_cvt_pkrtz(sc[t][2], sc[t][3]));
        pa[kh][j*4+0] = p01[0]; pa[kh][j*4+1] = p01[1];
        pa[kh][j*4+2] = p23[0]; pa[kh][j*4+3] = p23[1];
      }
    // PV: O[q][d] += P[q][kpos] * V[kpos][d]
    #pragma unroll
    for (int di = 0; di < 4; ++di){
      int d = di*16 + lm;
      int swz = (d & 7) << 4;
      #pragma unroll
      for (int kh = 0; kh < 2; ++kh){
        half4 lo = *(const half4*)(Vlds + d*128 + ((kh*64 + g*8)      ^ swz));
        half4 hi = *(const half4*)(Vlds + d*128 + ((kh*64 + g*8 + 32) ^ swz));
        half8 vf = { lo[0], lo[1], lo[2], lo[3], hi[0], hi[1], hi[2], hi[3] };
        O[di] = __builtin_amdgcn_mfma_f32_16x16x32_f16(pa[kh], vf, O[di], 0, 0, 0);
      }
    }
    __builtin_amdgcn_s_barrier();
  }

  const int b = bh >> 4, h = bh & 15;
  float inv = 1.f / lrun;
  float irow[4];
  #pragma unroll
  for (int r = 0; r < 4; ++r) irow[r] = __shfl(inv, (lane & 48) | (g*4 + r));
  #pragma unroll
  for (int di = 0; di < 4; ++di)
    #pragma unroll
    for (int r = 0; r < 4; ++r){
      long q = q0 + g*4 + r;
      AO[((long)b*1024 + q)*1024 + h*64 + di*16 + lm] = f2h(O[di][r] * irow[r]);
    }
}

// O-projection: out = AO @ Wo^T + bo, f32 output. 256 blocks (1/CU) -> dbuf pipe.
__global__ __launch_bounds__(256)
void gemm_o(const u16* __restrict__ A, const u16* __restrict__ Bt,
            const float* __restrict__ bias, float* __restrict__ outF)
{
  __shared__ __align__(128) char lds[65536];
  const int tid = threadIdx.x, lane = tid & 63, w = tid >> 6;
  const int g = lane >> 4, lm = lane & 15;
  int bid = (blockIdx.x & 7) * 32 + (blockIdx.x >> 3);    // 256 = 8 * 32
  const int rb = bid >> 3, cb = bid & 7;
  const int row0 = rb * 128, col0 = cb * 128;

  f32x4 acc[4][4];
  #pragma unroll
  for (int i = 0; i < 4; ++i)
    #pragma unroll
    for (int j = 0; j < 4; ++j) acc[i][j] = {0.f, 0.f, 0.f, 0.f};

  gemm128<true>(A, Bt, 1024, row0, col0, tid, lds, acc);

  const int wr = (w >> 1) * 64, wc = (w & 1) * 64;
  #pragma unroll
  for (int mi = 0; mi < 4; ++mi)
    #pragma unroll
    for (int ni = 0; ni < 4; ++ni){
      int n = col0 + wc + ni*16 + lm;
      float bvv = bias[n];
      #pragma unroll
      for (int r = 0; r < 4; ++r){
        int m = row0 + wr + mi*16 + g*4 + r;
        outF[(long)m * 1024 + n] = acc[mi][ni][r] + bvv;
      }
    }
}

extern "C" void kernel_launch(void* const* d_in, const int* in_sizes, int n_in,
                              void* d_out, int out_size, void* d_ws, size_t ws_size,
                              hipStream_t stream)
{
  const float* query = (const float*)d_in[0];
  const float* key   = (const float*)d_in[1];
  const float* value = (const float*)d_in[2];
  const float* Wq = (const float*)d_in[3];
  const float* bq = (const float*)d_in[4];
  const float* Wk = (const float*)d_in[5];
  const float* bk = (const float*)d_in[6];
  const float* Wv = (const float*)d_in[7];
  const float* bv = (const float*)d_in[8];
  const float* Wo = (const float*)d_in[9];
  const float* bo = (const float*)d_in[10];
  float* out = (float*)d_out;

  char* p = (char*)d_ws;
  auto alloc = [&](long bytes){ char* r = p; p += bytes; return r; };
  u16* qH  = (u16*)alloc( 8l<<20);   // [4096][1024] fp16
  u16* kH  = (u16*)alloc(12l<<20);   // [8192][768]
  u16* vH  = (u16*)alloc(12l<<20);   // [8192][768]
  u16* WqH = (u16*)alloc( 2l<<20);   // [1024][1024]
  u16* WkH = (u16*)alloc( 2l<<20);   // [1024][768]
  u16* WvH = (u16*)alloc( 2l<<20);   // [1024][768]
  u16* WoH = (u16*)alloc( 2l<<20);   // [1024][1024]
  u16* Qw  = (u16*)alloc( 8l<<20);   // [64][1024][64]
  u16* Kw  = (u16*)alloc(16l<<20);   // [64][2048][64]
  u16* Vtw = (u16*)alloc(16l<<20);   // [64][64][2048]
  u16* AO  = (u16*)alloc( 8l<<20);   // [4096][1024]

  Cvt7 ca;
  ca.seg[0] = { query, qH,  4096*1024/4 };
  ca.seg[1] = { key,   kH,  8192*768/4  };
  ca.seg[2] = { value, vH,  8192*768/4  };
  ca.seg[3] = { Wq,    WqH, 1024*1024/4 };
  ca.seg[4] = { Wk,    WkH, 1024*768/4  };
  ca.seg[5] = { Wv,    WvH, 1024*768/4  };
  ca.seg[6] = { Wo,    WoH, 1024*1024/4 };
  cvt_f32_f16<<<dim3(512, 7), 256, 0, stream>>>(ca);

  qkv_proj<<<dim3(1280), dim3(256), 0, stream>>>(qH, kH, vH, WqH, WkH, WvH,
                                                 bq, bk, bv, Qw, Kw, Vtw);
  attn_fused<<<dim3(512), dim3(512), 0, stream>>>(Qw, Kw, Vtw, AO);
  gemm_o<<<dim3(256), dim3(256), 0, stream>>>(AO, WoH, bo, out);
}